// Round 2
// baseline (291.366 us; speedup 1.0000x reference)
//
#include <hip/hip_runtime.h>

typedef unsigned int u32;
typedef unsigned long long u64;

#define NB 32
#define NCLS 80
#define NANCHOR 8400
#define PRE 1000
#define MAXDET 100
#define NTH 256   // nms block threads (4 waves -> cheap barriers)

// ---------------------------------------------------------------------------
// Kernel 1: decode. Block = 256 threads = 4 waves; each block handles 64
// consecutive anchors of one image; wave w reduces classes [20w, 20w+20).
// Level boundaries (6400, 8000) are multiples of 64, so a block never
// straddles levels. All class-plane loads are 64-lane coalesced (256B).
// ---------------------------------------------------------------------------
__global__ __launch_bounds__(256) void decode_kernel(
        const float* __restrict__ cls0, const float* __restrict__ box0,
        const float* __restrict__ cls1, const float* __restrict__ box1,
        const float* __restrict__ cls2, const float* __restrict__ box2,
        float* __restrict__ ws_scores, float4* __restrict__ ws_boxes,
        int* __restrict__ ws_cls) {
    const int blk = blockIdx.x;          // 32 images * 132 anchor-blocks
    const int b = blk / 132;
    const int ab = blk - b * 132;
    const int a0 = ab * 64;
    const int lane = threadIdx.x & 63;
    const int wv = threadIdx.x >> 6;

    const float* cp; const float* bp;
    int HW, W, step, hw0;
    if (a0 < 6400) {
        cp = cls0 + (size_t)b * NCLS * 6400; bp = box0 + (size_t)b * 4 * 6400;
        HW = 6400; W = 80; step = 8;  hw0 = a0;
    } else if (a0 < 8000) {
        cp = cls1 + (size_t)b * NCLS * 1600; bp = box1 + (size_t)b * 4 * 1600;
        HW = 1600; W = 40; step = 16; hw0 = a0 - 6400;
    } else {
        cp = cls2 + (size_t)b * NCLS * 400;  bp = box2 + (size_t)b * 4 * 400;
        HW = 400;  W = 20; step = 32; hw0 = a0 - 8000;
    }

    const int hw = hw0 + lane;
    const bool valid = hw < HW;

    __shared__ float s_pm[256];
    __shared__ int   s_pc[256];

    float m = -1e30f; int ci = 20 * wv;
    if (valid) {
        const float* cw = cp + (size_t)(20 * wv) * HW + hw;
        m = cw[0];
        #pragma unroll
        for (int c = 1; c < 20; ++c) {
            float v = cw[(size_t)c * HW];
            if (v > m) { m = v; ci = 20 * wv + c; }
        }
    }
    s_pm[threadIdx.x] = m;
    s_pc[threadIdx.x] = ci;
    __syncthreads();

    if (threadIdx.x < 64 && valid) {
        // combine class-groups in ascending order, strict > => first-occurrence argmax
        #pragma unroll
        for (int w = 1; w < 4; ++w) {
            float v = s_pm[w * 64 + lane];
            if (v > m) { m = v; ci = s_pc[w * 64 + lane]; }
        }
        float score = 1.0f / (1.0f + expf(-m));
        float l_ = bp[hw], t_ = bp[HW + hw], r_ = bp[2 * HW + hw], bo = bp[3 * HW + hw];
        int hh = hw / W, ww = hw - hh * W;
        float gx = (float)(ww * step), gy = (float)(hh * step);
        int g = b * NANCHOR + a0 + lane;
        ws_scores[g] = score;
        ws_boxes[g] = make_float4(gx - l_, gy - t_, gx + r_, gy + bo);
        ws_cls[g] = ci;
    }
}

// wave-level inclusive suffix scan (sum over lanes >= my lane)
__device__ __forceinline__ int wave_suffix_incl(int v, int lane) {
    #pragma unroll
    for (int off = 1; off < 64; off <<= 1) {
        int t = __shfl_down(v, off);
        if (lane + off < 64) v += t;
    }
    return v;
}

// ---------------------------------------------------------------------------
// Kernel 2: per-image select + sort + NMS. 256 threads (4 waves).
// Radix-select threshold (2x 10-bit passes, shuffle-scans), compact,
// bitonic-sort 2048 u64 keys, then BARRIER-FREE single-wave greedy NMS with
// register-cached boxes and register suppression bitmask.
// ---------------------------------------------------------------------------
__global__ __launch_bounds__(NTH) void nms_kernel(const float* __restrict__ ws_scores,
                                                  const float4* __restrict__ ws_boxes,
                                                  const int* __restrict__ ws_cls,
                                                  float* __restrict__ out) {
    const int b = blockIdx.x;
    const int tid = threadIdx.x;
    const int lane = tid & 63;
    const int wv = tid >> 6;

    __shared__ int s_hist[1024];
    __shared__ u64 s_key[2048];
    __shared__ float4 s_box[PRE];
    __shared__ float s_area[PRE];
    __shared__ int s_keep[MAXDET];
    __shared__ int s_wtot[4];
    __shared__ int s_C, s_base;
    __shared__ u32 s_thresh;
    __shared__ int s_cnt, s_nkept;

    const float* sc = ws_scores + (size_t)b * NANCHOR;

    // ---- load all score bits into registers (coalesced), clear hist
    u32 sb[33];
    #pragma unroll
    for (int k = 0; k < 33; ++k) {
        int a = tid + (k << 8);
        sb[k] = (a < NANCHOR) ? __float_as_uint(sc[a]) : 0u;
    }
    *(int4*)&s_hist[4 * tid] = make_int4(0, 0, 0, 0);
    __syncthreads();

    // ---- coarse histogram on bits [29:20]
    #pragma unroll
    for (int k = 0; k < 33; ++k) {
        int a = tid + (k << 8);
        if (a < NANCHOR) atomicAdd(&s_hist[sb[k] >> 20], 1);
    }
    __syncthreads();

    // ---- suffix scan (2 barriers)
    {
        int b0 = s_hist[4 * tid], b1 = s_hist[4 * tid + 1], b2 = s_hist[4 * tid + 2], b3 = s_hist[4 * tid + 3];
        int l3 = b3, l2 = b2 + b3, l1 = b1 + l2, l0 = b0 + l1;
        int wincl = wave_suffix_incl(l0, lane);
        if (lane == 0) s_wtot[wv] = wincl;
        int add = wincl - l0;
        __syncthreads();
        #pragma unroll
        for (int w = 0; w < 4; ++w) if (w > wv) add += s_wtot[w];
        s_hist[4 * tid] = l0 + add; s_hist[4 * tid + 1] = l1 + add;
        s_hist[4 * tid + 2] = l2 + add; s_hist[4 * tid + 3] = l3 + add;
        __syncthreads();
    }
    #pragma unroll
    for (int k = 0; k < 4; ++k) {
        int bin = 4 * tid + k;
        int sfx = s_hist[bin];
        int nxt = (bin < 1023) ? s_hist[bin + 1] : 0;
        if (sfx >= PRE && nxt < PRE) { s_C = bin; s_base = nxt; }
    }
    __syncthreads();
    const int C = s_C, base = s_base;
    *(int4*)&s_hist[4 * tid] = make_int4(0, 0, 0, 0);
    if (tid == 0) s_cnt = 0;
    #pragma unroll
    for (int k = 0; k < 8; ++k) s_key[tid + (k << 8)] = 0ULL;   // zero sort pads
    __syncthreads();

    // ---- fine histogram on bits [19:10] within coarse bin C
    #pragma unroll
    for (int k = 0; k < 33; ++k) {
        int a = tid + (k << 8);
        if (a < NANCHOR && (int)(sb[k] >> 20) == C) atomicAdd(&s_hist[(sb[k] >> 10) & 1023], 1);
    }
    __syncthreads();
    {
        int b0 = s_hist[4 * tid], b1 = s_hist[4 * tid + 1], b2 = s_hist[4 * tid + 2], b3 = s_hist[4 * tid + 3];
        int l3 = b3, l2 = b2 + b3, l1 = b1 + l2, l0 = b0 + l1;
        int wincl = wave_suffix_incl(l0, lane);
        if (lane == 0) s_wtot[wv] = wincl;
        int add = wincl - l0;
        __syncthreads();
        #pragma unroll
        for (int w = 0; w < 4; ++w) if (w > wv) add += s_wtot[w];
        s_hist[4 * tid] = l0 + add; s_hist[4 * tid + 1] = l1 + add;
        s_hist[4 * tid + 2] = l2 + add; s_hist[4 * tid + 3] = l3 + add;
        __syncthreads();
    }
    #pragma unroll
    for (int k = 0; k < 4; ++k) {
        int f = 4 * tid + k;
        int full = base + s_hist[f];
        int nxtf = base + ((f < 1023) ? s_hist[f + 1] : 0);
        if (full >= PRE && nxtf < PRE) s_thresh = ((u32)C << 20) | ((u32)f << 10);
    }
    __syncthreads();
    const u32 T = s_thresh;

    // ---- compact all candidates with scorebits >= T (prefix-closed, >= 1000)
    #pragma unroll
    for (int k = 0; k < 33; ++k) {
        int a = tid + (k << 8);
        if (a < NANCHOR && sb[k] >= T) {
            int pos = atomicAdd(&s_cnt, 1);
            if (pos < 2048)
                s_key[pos] = ((u64)sb[k] << 14) | (u64)(NANCHOR - 1 - a); // desc score, asc idx
        }
    }
    __syncthreads();

    // ---- bitonic sort 2048 keys descending (zero pads sink to the end)
    for (int k = 2; k <= 2048; k <<= 1) {
        for (int j = k >> 1; j > 0; j >>= 1) {
            #pragma unroll
            for (int i = tid; i < 2048; i += NTH) {
                int ixj = i ^ j;
                if (ixj > i) {
                    u64 va = s_key[i], vb = s_key[ixj];
                    bool desc = ((i & k) == 0);
                    if (desc ? (va < vb) : (va > vb)) { s_key[i] = vb; s_key[ixj] = va; }
                }
            }
            __syncthreads();
        }
    }

    // ---- stage top-1000 offset boxes + areas to LDS
    for (int r = tid; r < PRE; r += NTH) {
        u64 key = s_key[r];
        int idx = (NANCHOR - 1) - (int)(key & 16383ULL);
        float4 bx = ws_boxes[(size_t)b * NANCHOR + idx];
        int c = ws_cls[(size_t)b * NANCHOR + idx];
        float off = (float)c * 4096.0f;
        float x1 = bx.x + off, y1 = bx.y + off, x2 = bx.z + off, y2 = bx.w + off;
        s_box[r] = make_float4(x1, y1, x2, y2);
        s_area[r] = fmaxf(x2 - x1, 0.0f) * fmaxf(y2 - y1, 0.0f);
    }
    if (tid == 0) s_nkept = 0;
    __syncthreads();

    // ---- barrier-free greedy NMS on wave 0.
    // Lane l owns rows {l, l+64, ..., l+960}: boxes cached in registers,
    // suppression flags in a 16-bit register mask. Row-i flag via shfl.
    if (wv == 0) {
        float jx1[16], jy1[16], jx2[16], jy2[16], ja[16];
        #pragma unroll
        for (int k = 0; k < 16; ++k) {
            int j = lane + (k << 6);
            if (j < PRE) {
                float4 v = s_box[j];
                jx1[k] = v.x; jy1[k] = v.y; jx2[k] = v.z; jy2[k] = v.w;
                ja[k] = s_area[j];
            } else {
                jx1[k] = 3.0e8f; jy1[k] = 3.0e8f; jx2[k] = 3.0e8f; jy2[k] = 3.0e8f;
                ja[k] = 0.0f;
            }
        }
        u32 supp = 0;
        int nkept = 0;
        for (int i = 0; i < PRE; ++i) {
            int owner = i & 63, kk = i >> 6;
            u32 um = (u32)__shfl((int)supp, owner);
            if ((um >> kk) & 1) continue;            // wave-uniform
            if (lane == 0) s_keep[nkept] = i;
            nkept++;
            if (nkept >= MAXDET) break;
            float4 bi = s_box[i];                    // broadcast LDS read
            float ai = s_area[i];
            #pragma unroll
            for (int k = 0; k < 16; ++k) {
                int j = lane + (k << 6);
                bool act = (j > i) && (j < PRE) && !((supp >> k) & 1);
                float lx = fmaxf(bi.x, jx1[k]);
                float ly = fmaxf(bi.y, jy1[k]);
                float rx = fminf(bi.z, jx2[k]);
                float ry = fminf(bi.w, jy2[k]);
                float wx = fmaxf(rx - lx, 0.0f);
                float wy = fmaxf(ry - ly, 0.0f);
                float inter = wx * wy;
                float den = ai + ja[k] - inter + 1e-7f;  // ((ai+aj)-inter)+eps
                if (act && (inter > 0.5f * den)) supp |= (1u << k);
            }
        }
        if (lane == 0) s_nkept = nkept;
    }
    __syncthreads();

    // ---- outputs: boxes_with_scores [32][100][5], then classes [32][100]
    const int nk = s_nkept;
    if (tid < MAXDET) {
        float* o = out + ((size_t)b * MAXDET + tid) * 5;
        float* oc = out + (size_t)NB * MAXDET * 5 + (size_t)b * MAXDET + tid;
        if (tid < nk) {
            int i = s_keep[tid];
            u64 key = s_key[i];
            int idx = (NANCHOR - 1) - (int)(key & 16383ULL);
            float score = __uint_as_float((u32)(key >> 14));
            float4 bx = ws_boxes[(size_t)b * NANCHOR + idx];
            int c = ws_cls[(size_t)b * NANCHOR + idx];
            o[0] = bx.x; o[1] = bx.y; o[2] = bx.z; o[3] = bx.w; o[4] = score;
            *oc = (float)c;
        } else {
            o[0] = 0.0f; o[1] = 0.0f; o[2] = 0.0f; o[3] = 0.0f; o[4] = 0.0f;
            *oc = -1.0f;
        }
    }
}

extern "C" void kernel_launch(void* const* d_in, const int* in_sizes, int n_in,
                              void* d_out, int out_size, void* d_ws, size_t ws_size,
                              hipStream_t stream) {
    const float* cls0 = (const float*)d_in[0];
    const float* box0 = (const float*)d_in[1];
    const float* cls1 = (const float*)d_in[2];
    const float* box1 = (const float*)d_in[3];
    const float* cls2 = (const float*)d_in[4];
    const float* box2 = (const float*)d_in[5];

    float* ws = (float*)d_ws;
    float* ws_scores = ws;                                   // 268800 floats
    float4* ws_boxes = (float4*)(ws + NB * NANCHOR);         // 268800 float4
    int* ws_cls = (int*)(ws + (size_t)NB * NANCHOR * 5);     // 268800 ints

    decode_kernel<<<NB * 132, 256, 0, stream>>>(
        cls0, box0, cls1, box1, cls2, box2, ws_scores, ws_boxes, ws_cls);

    nms_kernel<<<NB, NTH, 0, stream>>>(ws_scores, ws_boxes, ws_cls, (float*)d_out);
}

// Round 3
// 275.669 us; speedup vs baseline: 1.0569x; 1.0569x over previous
//
#include <hip/hip_runtime.h>

typedef unsigned int u32;
typedef unsigned long long u64;

#define NB 32
#define NCLS 80
#define NANCHOR 8400
#define PRE 1000
#define MAXDET 100

// ws layout (floats):
//   [0 .. 268800)            scores[b][a]   (decode out; REUSED per image b for sorted data)
//   [268800 .. 268800+4*268800) boxes float4[b][a]
//   [5*268800 .. 6*268800)   cls int[b][a]
// Per-image sorted region (reuses scores area, float offset b*8400):
//   sbox  float4[1024]  (4096 floats)
//   skey  u64[1024]     (2048 floats)
//   sarea float[1024]   (1024 floats)   total 7168 < 8400

// ---------------------------------------------------------------------------
// Kernel 1: decode. One thread per (image, anchor). (R1 version — proven.)
// ---------------------------------------------------------------------------
__global__ void decode_kernel(const float* __restrict__ cls0, const float* __restrict__ box0,
                              const float* __restrict__ cls1, const float* __restrict__ box1,
                              const float* __restrict__ cls2, const float* __restrict__ box2,
                              float* __restrict__ ws_scores, float4* __restrict__ ws_boxes,
                              int* __restrict__ ws_cls) {
    int g = blockIdx.x * blockDim.x + threadIdx.x;
    if (g >= NB * NANCHOR) return;
    int b = g / NANCHOR;
    int r = g - b * NANCHOR;

    const float* cp; const float* bp;
    int HW, hw, h, w, step;
    if (r < 6400) {
        cp = cls0 + (size_t)b * NCLS * 6400; bp = box0 + (size_t)b * 4 * 6400;
        HW = 6400; hw = r;        h = hw / 80; w = hw - h * 80; step = 8;
    } else if (r < 8000) {
        cp = cls1 + (size_t)b * NCLS * 1600; bp = box1 + (size_t)b * 4 * 1600;
        HW = 1600; hw = r - 6400; h = hw / 40; w = hw - h * 40; step = 16;
    } else {
        cp = cls2 + (size_t)b * NCLS * 400;  bp = box2 + (size_t)b * 4 * 400;
        HW = 400;  hw = r - 8000; h = hw / 20; w = hw - h * 20; step = 32;
    }

    float m = cp[hw];
    int ci = 0;
    for (int c = 1; c < NCLS; ++c) {
        float v = cp[(size_t)c * HW + hw];
        if (v > m) { m = v; ci = c; }
    }
    float score = 1.0f / (1.0f + expf(-m));

    float l = bp[hw], t = bp[HW + hw], rr = bp[2 * HW + hw], bo = bp[3 * HW + hw];
    float gx = (float)(w * step), gy = (float)(h * step);

    ws_scores[g] = score;
    ws_boxes[g] = make_float4(gx - l, gy - t, gx + rr, gy + bo);
    ws_cls[g] = ci;
}

// wave-level inclusive suffix scan (sum over lanes >= my lane)
__device__ __forceinline__ int wave_suffix_incl(int v, int lane) {
    #pragma unroll
    for (int off = 1; off < 64; off <<= 1) {
        int t = __shfl_down(v, off);
        if (lane + off < 64) v += t;
    }
    return v;
}

// ---------------------------------------------------------------------------
// Kernel 2: per-image radix-select threshold + compact + O(n^2) RANK SORT.
// 1024 threads (16 waves). ~8 barriers total. Writes sorted offset-boxes,
// areas, and keys to ws (reusing this image's scores region).
// ---------------------------------------------------------------------------
__global__ __launch_bounds__(1024) void select_kernel(float* ws,
                                                      const float4* __restrict__ ws_boxes,
                                                      const int* __restrict__ ws_cls) {
    const int b = blockIdx.x;
    const int tid = threadIdx.x;
    const int lane = tid & 63;
    const int wv = tid >> 6;

    __shared__ int s_hist[4][1024];   // 16 KB, 4 sub-histograms vs same-address atomics
    __shared__ u64 s_key[2048];       // 16 KB
    __shared__ int s_wtot[16];
    __shared__ int s_C, s_base, s_cnt;
    __shared__ u32 s_thresh;

    const float* sc = ws + (size_t)b * NANCHOR;
    float4* sbox = (float4*)(ws + (size_t)b * NANCHOR);
    u64*    skey = (u64*)(ws + (size_t)b * NANCHOR + 4096);
    float*  sarea = ws + (size_t)b * NANCHOR + 6144;

    // load all score bits (positive floats -> bit order == value order)
    u32 sb[9];
    #pragma unroll
    for (int k = 0; k < 9; ++k) {
        int a = tid + (k << 10);
        sb[k] = (a < NANCHOR) ? __float_as_uint(sc[a]) : 0u;
    }
    int* hp = &s_hist[0][0];
    hp[tid] = 0; hp[tid + 1024] = 0; hp[tid + 2048] = 0; hp[tid + 3072] = 0;
    if (tid == 0) s_cnt = 0;
    __syncthreads();                                        // B1

    // coarse histogram on bits [29:20]
    #pragma unroll
    for (int k = 0; k < 9; ++k) {
        int a = tid + (k << 10);
        if (a < NANCHOR) atomicAdd(&s_hist[wv & 3][sb[k] >> 20], 1);
    }
    __syncthreads();                                        // B2
    {
        int v = s_hist[0][tid] + s_hist[1][tid] + s_hist[2][tid] + s_hist[3][tid];
        int wincl = wave_suffix_incl(v, lane);
        if (lane == 0) s_wtot[wv] = wincl;
        __syncthreads();                                    // B3
        int add = 0;
        #pragma unroll
        for (int w = 0; w < 16; ++w) if (w > wv) add += s_wtot[w];
        int sfx = wincl + add;      // suffix sum including bin tid
        int nxt = sfx - v;          // suffix sum at bin tid+1
        if (sfx >= PRE && nxt < PRE) { s_C = tid; s_base = nxt; }
        hp[tid] = 0; hp[tid + 1024] = 0; hp[tid + 2048] = 0; hp[tid + 3072] = 0;
    }
    __syncthreads();                                        // B4
    const int C = s_C, base0 = s_base;

    // fine histogram on bits [19:10] within coarse bin C
    #pragma unroll
    for (int k = 0; k < 9; ++k) {
        int a = tid + (k << 10);
        if (a < NANCHOR && (int)(sb[k] >> 20) == C)
            atomicAdd(&s_hist[wv & 3][(sb[k] >> 10) & 1023], 1);
    }
    __syncthreads();                                        // B5
    {
        int v = s_hist[0][tid] + s_hist[1][tid] + s_hist[2][tid] + s_hist[3][tid];
        int wincl = wave_suffix_incl(v, lane);
        if (lane == 0) s_wtot[wv] = wincl;
        __syncthreads();                                    // B6
        int add = 0;
        #pragma unroll
        for (int w = 0; w < 16; ++w) if (w > wv) add += s_wtot[w];
        int sfx = wincl + add;
        int nxt = sfx - v;
        if (base0 + sfx >= PRE && base0 + nxt < PRE)
            s_thresh = ((u32)C << 20) | ((u32)tid << 10);
    }
    __syncthreads();                                        // B7
    const u32 T = s_thresh;

    // compact candidates (scorebits >= T; prefix-closed, >= 1000).
    // Ballot-aggregated push: 1 LDS atomic per wave per chunk. Order is
    // irrelevant — rank sort below assigns exact positions.
    #pragma unroll
    for (int k = 0; k < 9; ++k) {
        int a = tid + (k << 10);
        bool pred = (a < NANCHOR) && (sb[k] >= T);
        u64 mask = __ballot(pred);
        if (pred) {
            int leader = __ffsll(mask) - 1;
            int bpos = 0;
            if (lane == leader) bpos = atomicAdd(&s_cnt, __popcll(mask));
            bpos = __shfl(bpos, leader);
            int pos = bpos + __popcll(mask & ((1ULL << lane) - 1ULL));
            if (pos < 2048)
                s_key[pos] = ((u64)sb[k] << 14) | (u64)(NANCHOR - 1 - a); // desc score, asc idx
        }
    }
    __syncthreads();                                        // B8

    // rank sort: position of key x (descending) = #{y : key_y > key_x}.
    // Keys unique (index tiebreak) -> exact permutation, identical order to
    // the R1/R2 bitonic sort. All LDS reads are wave-broadcast.
    int cnt = s_cnt; if (cnt > 2048) cnt = 2048;
    for (int slot = tid; slot < cnt; slot += 1024) {
        u64 me = s_key[slot];
        int rank = 0;
        int y = 0;
        for (; y + 4 <= cnt; y += 4) {
            rank += (int)(s_key[y] > me) + (int)(s_key[y + 1] > me)
                  + (int)(s_key[y + 2] > me) + (int)(s_key[y + 3] > me);
        }
        for (; y < cnt; ++y) rank += (int)(s_key[y] > me);
        if (rank < PRE) {
            int idx = (NANCHOR - 1) - (int)(me & 16383ULL);
            float4 bx = ws_boxes[(size_t)b * NANCHOR + idx];
            int c = ws_cls[(size_t)b * NANCHOR + idx];
            float off = (float)c * 4096.0f;                 // batched-NMS class offset
            float x1 = bx.x + off, y1 = bx.y + off, x2 = bx.z + off, y2 = bx.w + off;
            sbox[rank] = make_float4(x1, y1, x2, y2);
            sarea[rank] = fmaxf(x2 - x1, 0.0f) * fmaxf(y2 - y1, 0.0f);
            skey[rank] = me;
        }
    }
}

// ---------------------------------------------------------------------------
// Kernel 3: single-wave barrier-free greedy NMS (R2's proven-exact loop).
// 64 threads/block; lane l owns rows {l+64k}, boxes in registers,
// suppression bits in a register mask; row-i flag via shfl.
// ---------------------------------------------------------------------------
__global__ __launch_bounds__(64) void nms_kernel(const float* __restrict__ ws,
                                                 const float4* __restrict__ ws_boxes,
                                                 const int* __restrict__ ws_cls,
                                                 float* __restrict__ out) {
    const int b = blockIdx.x;
    const int lane = threadIdx.x;

    const float4* sbox = (const float4*)(ws + (size_t)b * NANCHOR);
    const u64*    skey = (const u64*)(ws + (size_t)b * NANCHOR + 4096);
    const float*  sarea = ws + (size_t)b * NANCHOR + 6144;

    __shared__ float4 s_box[PRE];
    __shared__ float s_area[PRE];
    __shared__ int s_keep[MAXDET];

    float jx1[16], jy1[16], jx2[16], jy2[16], ja[16];
    #pragma unroll
    for (int k = 0; k < 16; ++k) {
        int j = lane + (k << 6);
        if (j < PRE) {
            float4 v = sbox[j];
            float a = sarea[j];
            s_box[j] = v; s_area[j] = a;
            jx1[k] = v.x; jy1[k] = v.y; jx2[k] = v.z; jy2[k] = v.w; ja[k] = a;
        } else {
            jx1[k] = 3.0e8f; jy1[k] = 3.0e8f; jx2[k] = 3.0e8f; jy2[k] = 3.0e8f;
            ja[k] = 0.0f;
        }
    }
    __syncthreads();

    u32 supp = 0;
    int nkept = 0;
    for (int i = 0; i < PRE; ++i) {
        int owner = i & 63, kk = i >> 6;
        u32 um = (u32)__shfl((int)supp, owner);
        if ((um >> kk) & 1) continue;            // wave-uniform
        if (lane == 0) s_keep[nkept] = i;
        nkept++;
        if (nkept >= MAXDET) break;
        float4 bi = s_box[i];                    // LDS broadcast
        float ai = s_area[i];
        #pragma unroll
        for (int k = 0; k < 16; ++k) {
            int j = lane + (k << 6);
            bool act = (j > i) && (j < PRE) && !((supp >> k) & 1);
            float lx = fmaxf(bi.x, jx1[k]);
            float ly = fmaxf(bi.y, jy1[k]);
            float rx = fminf(bi.z, jx2[k]);
            float ry = fminf(bi.w, jy2[k]);
            float wx = fmaxf(rx - lx, 0.0f);
            float wy = fmaxf(ry - ly, 0.0f);
            float inter = wx * wy;
            float den = ai + ja[k] - inter + 1e-7f;     // ((ai+aj)-inter)+eps
            if (act && (inter > 0.5f * den)) supp |= (1u << k);
        }
    }
    __syncthreads();

    // outputs: boxes_with_scores [32][100][5], then classes [32][100]
    #pragma unroll
    for (int t = 0; t < 2; ++t) {
        int r = lane + (t << 6);
        if (r < MAXDET) {
            float* o = out + ((size_t)b * MAXDET + r) * 5;
            float* oc = out + (size_t)NB * MAXDET * 5 + (size_t)b * MAXDET + r;
            if (r < nkept) {
                int i = s_keep[r];
                u64 key = skey[i];
                int idx = (NANCHOR - 1) - (int)(key & 16383ULL);
                float score = __uint_as_float((u32)(key >> 14));
                float4 bx = ws_boxes[(size_t)b * NANCHOR + idx];
                int c = ws_cls[(size_t)b * NANCHOR + idx];
                o[0] = bx.x; o[1] = bx.y; o[2] = bx.z; o[3] = bx.w; o[4] = score;
                *oc = (float)c;
            } else {
                o[0] = 0.0f; o[1] = 0.0f; o[2] = 0.0f; o[3] = 0.0f; o[4] = 0.0f;
                *oc = -1.0f;
            }
        }
    }
}

extern "C" void kernel_launch(void* const* d_in, const int* in_sizes, int n_in,
                              void* d_out, int out_size, void* d_ws, size_t ws_size,
                              hipStream_t stream) {
    const float* cls0 = (const float*)d_in[0];
    const float* box0 = (const float*)d_in[1];
    const float* cls1 = (const float*)d_in[2];
    const float* box1 = (const float*)d_in[3];
    const float* cls2 = (const float*)d_in[4];
    const float* box2 = (const float*)d_in[5];

    float* ws = (float*)d_ws;
    float* ws_scores = ws;                                   // 268800 floats (reused for sorted data)
    float4* ws_boxes = (float4*)(ws + NB * NANCHOR);         // 268800 float4
    int* ws_cls = (int*)(ws + (size_t)NB * NANCHOR * 5);     // 268800 ints

    int total = NB * NANCHOR;
    decode_kernel<<<(total + 255) / 256, 256, 0, stream>>>(
        cls0, box0, cls1, box1, cls2, box2, ws_scores, ws_boxes, ws_cls);

    select_kernel<<<NB, 1024, 0, stream>>>(ws, ws_boxes, ws_cls);

    nms_kernel<<<NB, 64, 0, stream>>>(ws, ws_boxes, ws_cls, (float*)d_out);
}